// Round 4
// baseline (1308.744 us; speedup 1.0000x reference)
//
#include <hip/hip_runtime.h>
#include <hip/hip_cooperative_groups.h>
#include <cstdint>
#include <cstddef>

namespace cg = cooperative_groups;

#define D 128

typedef float v2f __attribute__((ext_vector_type(2)));

// ---------------- Threefry-2x32 (JAX/Random123), host+device ----------------
__host__ __device__ inline uint32_t rotl32(uint32_t v, int d) {
  return (v << d) | (v >> (32 - d));
}

__host__ __device__ inline void threefry2x32(uint32_t k0, uint32_t k1,
                                             uint32_t x0, uint32_t x1,
                                             uint32_t* o0, uint32_t* o1) {
  uint32_t k2 = k0 ^ k1 ^ 0x1BD11BDAu;
  x0 += k0; x1 += k1;
#define TF_RND(r) x0 += x1; x1 = rotl32(x1, (r)); x1 ^= x0;
  TF_RND(13) TF_RND(15) TF_RND(26) TF_RND(6)
  x0 += k1; x1 += k2 + 1u;
  TF_RND(17) TF_RND(29) TF_RND(16) TF_RND(24)
  x0 += k2; x1 += k0 + 2u;
  TF_RND(13) TF_RND(15) TF_RND(26) TF_RND(6)
  x0 += k0; x1 += k1 + 3u;
  TF_RND(17) TF_RND(29) TF_RND(16) TF_RND(24)
  x0 += k1; x1 += k2 + 4u;
  TF_RND(13) TF_RND(15) TF_RND(26) TF_RND(6)
  x0 += k2; x1 += k0 + 5u;
#undef TF_RND
  *o0 = x0; *o1 = x1;
}

// XLA ErfInv32 (Giles) — full-precision variant.
__device__ inline float erfinv_f32(float x) {
  float w = -log1pf(-x * x);
  float p;
  if (w < 5.0f) {
    w = w - 2.5f;
    p = 2.81022636e-08f;
    p = fmaf(p, w, 3.43273939e-07f);
    p = fmaf(p, w, -3.5233877e-06f);
    p = fmaf(p, w, -4.39150654e-06f);
    p = fmaf(p, w, 0.00021858087f);
    p = fmaf(p, w, -0.00125372503f);
    p = fmaf(p, w, -0.00417768164f);
    p = fmaf(p, w, 0.246640727f);
    p = fmaf(p, w, 1.50140941f);
  } else {
    w = sqrtf(w) - 3.0f;
    p = -0.000200214257f;
    p = fmaf(p, w, 0.000100950558f);
    p = fmaf(p, w, 0.00134934322f);
    p = fmaf(p, w, -0.00367342844f);
    p = fmaf(p, w, 0.00573950773f);
    p = fmaf(p, w, -0.0076224613f);
    p = fmaf(p, w, 0.00943887047f);
    p = fmaf(p, w, 1.00167406f);
    p = fmaf(p, w, 2.83297682f);
  }
  return p * x;
}

// Fast erfinv: same Giles polynomials, w = -ln(1-x^2) via exact-FMA + v_log.
// |δnoise| ~1e-7 << tolerance (verified passing rounds 2-3).
__device__ inline float erfinv_fast(float x) {
  float t = fmaf(-x, x, 1.0f);
  float w = -0.693147180559945f * __builtin_amdgcn_logf(t);
  float p;
  if (__builtin_expect(w < 5.0f, 1)) {
    w = w - 2.5f;
    p = 2.81022636e-08f;
    p = fmaf(p, w, 3.43273939e-07f);
    p = fmaf(p, w, -3.5233877e-06f);
    p = fmaf(p, w, -4.39150654e-06f);
    p = fmaf(p, w, 0.00021858087f);
    p = fmaf(p, w, -0.00125372503f);
    p = fmaf(p, w, -0.00417768164f);
    p = fmaf(p, w, 0.246640727f);
    p = fmaf(p, w, 1.50140941f);
  } else {
    w = __builtin_amdgcn_sqrtf(w) - 3.0f;
    p = -0.000200214257f;
    p = fmaf(p, w, 0.000100950558f);
    p = fmaf(p, w, 0.00134934322f);
    p = fmaf(p, w, -0.00367342844f);
    p = fmaf(p, w, 0.00573950773f);
    p = fmaf(p, w, -0.0076224613f);
    p = fmaf(p, w, 0.00943887047f);
    p = fmaf(p, w, 1.00167406f);
    p = fmaf(p, w, 2.83297682f);
  }
  return p * x;
}

__device__ inline float jax_normal_elem(uint32_t k0, uint32_t k1, uint32_t idx) {
  uint32_t o0, o1;
  threefry2x32(k0, k1, 0u, idx, &o0, &o1);
  uint32_t bits = o0 ^ o1;
  float f = __uint_as_float((bits >> 9) | 0x3F800000u) - 1.0f;
  float u = f * 2.0f + (-0.99999994f);
  u = fmaxf(-0.99999994f, u);
  return 1.41421356237309505f * erfinv_f32(u);
}

__device__ inline float jax_normal_fast(uint32_t k0, uint32_t k1, uint32_t idx) {
  uint32_t o0, o1;
  threefry2x32(k0, k1, 0u, idx, &o0, &o1);
  uint32_t bits = o0 ^ o1;
  float f = __uint_as_float((bits >> 9) | 0x3F800000u) - 1.0f;
  float u = f * 2.0f + (-0.99999994f);
  u = fmaxf(-0.99999994f, u);
  return 1.41421356237309505f * erfinv_fast(u);
}

__device__ inline uint32_t f32_to_bf16_rne(float f) {
  uint32_t u = __float_as_uint(f);
  u += 0x7fffu + ((u >> 16) & 1u);
  return u >> 16;
}

// One noise unit: 2048 elements (8/thread) of 0.1*normal for ONE hop key.
__device__ inline void gen_noise8(float* __restrict__ np, size_t NDl, int k,
                                  uint32_t k0, uint32_t k1) {
  size_t base = ((size_t)k * 256 + threadIdx.x) * 8;
  if (base + 8 <= NDl) {
    float vv[8];
#pragma unroll
    for (int i = 0; i < 8; ++i)
      vv[i] = 0.1f * jax_normal_fast(k0, k1, (uint32_t)base + (uint32_t)i);
    float4* q = (float4*)(np + base);
    q[0] = make_float4(vv[0], vv[1], vv[2], vv[3]);
    q[1] = make_float4(vv[4], vv[5], vv[6], vv[7]);
  }
}

// Bresenham work mixer: of T units, exactly Z are noise, spread evenly.
// Returns true (noise, *nz in [0,Z)) or false (*work in [0,T-Z)).
__device__ inline bool mix_role(int u, int T, int Z, int* work, int* nz) {
  long long a = (long long)u * Z;
  int before = (int)(a / T);
  int after = (int)((a + Z) / T);
  if (after > before) { *nz = before; return true; }
  *work = u - before;
  return false;
}

// Round-robin role split (fallback path, round-3 proven).
__device__ inline bool role_split(int bid, int s, int Z, int* work, int* nz) {
  int k = bid / s;
  int r = bid - k * s;
  if (r == s - 1 && k < Z) { *nz = k; return true; }
  *work = bid - min(k, Z);
  return false;
}

// ---------------- hop edge body (shared) ------------------------------------
union V8 { float4 v[2]; v2f d[4]; float f[8]; };
union U4B { uint4 v; uint32_t u[4]; };

__device__ inline void hop_edge_pk(const U4B& raw, const V8& b, V8& acc) {
  V8 af;
#pragma unroll
  for (int i = 0; i < 4; ++i) {
    af.f[2 * i] = __uint_as_float(raw.u[i] << 16);
    af.f[2 * i + 1] = __uint_as_float(raw.u[i] & 0xffff0000u);
  }
  v2f p2 = af.d[0] * b.d[0];
#pragma unroll
  for (int q = 1; q < 4; ++q) p2 = __builtin_elementwise_fma(af.d[q], b.d[q], p2);
  float part = p2.x + p2.y;
  part += __shfl_xor(part, 1);
  part += __shfl_xor(part, 2);
  part += __shfl_xor(part, 4);
  part += __shfl_xor(part, 8);
  float alpha = __builtin_amdgcn_rcpf(1.0f + __expf(-part));
  v2f av = { alpha, alpha };
#pragma unroll
  for (int q = 0; q < 4; ++q) acc.d[q] = __builtin_elementwise_fma(av, af.d[q], acc.d[q]);
}

// One hop row-group unit (16 rows x 16 lanes), bf16 gather + precomputed noise.
__device__ inline void hop_unit(int g, const float* __restrict__ hprev,
    const uint16_t* __restrict__ mprev, float* __restrict__ hout,
    uint16_t* __restrict__ mout, const int* __restrict__ offsets,
    const int* __restrict__ sorted_src, const int* __restrict__ perm,
    const float* __restrict__ noise, int N, int E) {
  int sub = threadIdx.x & 15;
  if (g >= N) return;
  int r = perm[g];
  size_t rbase = (size_t)r * D + sub * 8;

  V8 b;
  {
    const float4* p = (const float4*)(hprev + rbase);
    b.v[0] = p[0]; b.v[1] = p[1];
  }
  V8 acc;
#pragma unroll
  for (int i = 0; i < 8; ++i) acc.f[i] = 0.f;

  int j0 = offsets[r];
  int cnt = offsets[r + 1] - j0;
  int Em1 = E - 1;
  const char* mb = (const char*)mprev + (uint32_t)(sub * 16);

  U4B buf[4];
  int sNext[4];
#pragma unroll
  for (int q = 0; q < 4; ++q) {
    uint32_t s = (uint32_t)sorted_src[min(j0 + q, Em1)];
    buf[q].v = *(const uint4*)(mb + (s << 8));
  }
#pragma unroll
  for (int q = 0; q < 4; ++q) sNext[q] = sorted_src[min(j0 + 4 + q, Em1)];

  int cnt4 = cnt & ~3;
  for (int i = 0; i < cnt4; i += 4) {
#pragma unroll
    for (int q = 0; q < 4; ++q) {
      hop_edge_pk(buf[q], b, acc);
      buf[q].v = *(const uint4*)(mb + ((uint32_t)sNext[q] << 8));
      sNext[q] = sorted_src[min(j0 + i + 8 + q, Em1)];
    }
  }
  int rem = cnt - cnt4;
#pragma unroll
  for (int q = 0; q < 3; ++q)
    if (q < rem) hop_edge_pk(buf[q], b, acc);

  V8 nzv;
  {
    const float4* p = (const float4*)(noise + rbase);
    nzv.v[0] = p[0]; nzv.v[1] = p[1];
  }
  float ss = 0.f;
#pragma unroll
  for (int i2 = 0; i2 < 8; ++i2) {
    acc.f[i2] += nzv.f[i2];
    ss = fmaf(acc.f[i2], acc.f[i2], ss);
  }
  ss += __shfl_xor(ss, 1);
  ss += __shfl_xor(ss, 2);
  ss += __shfl_xor(ss, 4);
  ss += __shfl_xor(ss, 8);
  float denom = fmaxf(sqrtf(ss), 1e-12f);
  float inv = __builtin_amdgcn_rcpf(denom);
  inv = inv * fmaf(-denom, inv, 2.0f);
#pragma unroll
  for (int i2 = 0; i2 < 8; ++i2) acc.f[i2] *= inv;
  {
    float4* p = (float4*)(hout + rbase);
    p[0] = acc.v[0]; p[1] = acc.v[1];
  }
  if (mout) {
    U4B wq;
#pragma unroll
    for (int i2 = 0; i2 < 4; ++i2)
      wq.u[i2] = f32_to_bf16_rne(acc.f[2 * i2]) |
                 (f32_to_bf16_rne(acc.f[2 * i2 + 1]) << 16);
    *(uint4*)(mout + rbase) = wq.v;
  }
}

// ---------------- MEGA: the whole pipeline in one cooperative launch --------
struct MegaArgs {
  const float* x;
  const int* src;
  const int* dst;
  float* out;
  int* offsets;       // doubles as counts
  int* cursor;
  int* perm;
  int* deg;
  int* deg_hist;
  int* deg_cursor;
  int* blocksums;
  int* sorted_src;
  uint16_t* mir0;
  uint16_t* mir1;
  float* noise;       // 3 x N*D
  int N, E, E4, nbHist, nbNorm, nbScan, Zn, hopU;
  uint32_t k0a, k1a, k0b, k1b, k0c, k1c;
};

__global__ __launch_bounds__(256, 8) void mega_kernel(MegaArgs A) {
  cg::grid_group grid = cg::this_grid();
  __shared__ int sh_tmp[256];
  __shared__ int sh_a[1024];
  __shared__ int sh_b[1024];
  const int nb = gridDim.x;
  const int bid = blockIdx.x;
  const int tid = threadIdx.x;
  const size_t NDl = (size_t)A.N * D;

  // ---- Z: zero counts + deg_hist ----
  {
    int gt = bid * 256 + tid, gs = nb * 256;
    for (int i = gt; i < A.N + 1; i += gs) A.offsets[i] = 0;
    for (int i = gt; i < 1024; i += gs) A.deg_hist[i] = 0;
  }
  grid.sync();

  // ---- P0: hist + norm(out0+mir0) + noise[hop0], mixed ----
  {
    int T = A.nbHist + A.nbNorm + A.Zn;
    for (int u = bid; u < T; u += nb) {
      int w, nz;
      if (mix_role(u, T, A.Zn, &w, &nz)) {
        gen_noise8(A.noise, NDl, nz, A.k0a, A.k1a);
      } else if (w < A.nbHist) {
        int t = w * 256 + tid;
        if (t < A.E4) {
          int4 d4 = ((const int4*)A.dst)[t];
          atomicAdd(&A.offsets[d4.x], 1);
          atomicAdd(&A.offsets[d4.y], 1);
          atomicAdd(&A.offsets[d4.z], 1);
          atomicAdd(&A.offsets[d4.w], 1);
        }
        int rem = A.E4 * 4 + t;
        if (t < A.E - A.E4 * 4) atomicAdd(&A.offsets[A.dst[rem]], 1);
      } else {
        int t = (w - A.nbHist) * 256 + tid;
        int row = t >> 6;
        int lane = t & 63;
        if (row < A.N) {
          size_t base = (size_t)row * D + 2 * lane;
          float2 v = *(const float2*)(A.x + base);
          float ss = v.x * v.x + v.y * v.y;
#pragma unroll
          for (int off = 32; off > 0; off >>= 1) ss += __shfl_xor(ss, off);
          float denom = fmaxf(sqrtf(ss), 1e-12f);
          float2 o = make_float2(v.x / denom, v.y / denom);
          *(float2*)(A.out + base) = o;
          uint32_t wq = f32_to_bf16_rne(o.x) | (f32_to_bf16_rne(o.y) << 16);
          *(uint32_t*)(A.mir0 + base) = wq;
        }
      }
    }
  }
  grid.sync();

  // ---- P1: scanA over virtual blocks ----
  for (int vb = bid; vb < A.nbScan; vb += nb) {
    for (int b2 = tid; b2 < 1024; b2 += 256) sh_a[b2] = 0;
    int i = vb * 256 + tid;
    int v = (i < A.N) ? A.offsets[i] : 0;
    sh_tmp[tid] = v;
    __syncthreads();
    if (i < A.N) {
      A.deg[i] = v;
      atomicAdd(&sh_a[min(v, 1023)], 1);
    }
    for (int off = 1; off < 256; off <<= 1) {
      int t2 = (tid >= off) ? sh_tmp[tid - off] : 0;
      __syncthreads();
      sh_tmp[tid] += t2;
      __syncthreads();
    }
    if (i < A.N) A.offsets[i] = sh_tmp[tid] - v;  // exclusive
    if (tid == 255) A.blocksums[vb] = sh_tmp[tid];
    __syncthreads();
    for (int b2 = tid; b2 < 1024; b2 += 256) {
      int c = sh_a[b2];
      if (c) atomicAdd(&A.deg_hist[b2], c);
    }
    __syncthreads();
  }
  grid.sync();

  // ---- P2: scanB (block 0 only) ----
  if (bid == 0) {
    int v = (tid < A.nbScan) ? A.blocksums[tid] : 0;
    sh_tmp[tid] = v;
    __syncthreads();
    for (int off = 1; off < 256; off <<= 1) {
      int t2 = (tid >= off) ? sh_tmp[tid - off] : 0;
      __syncthreads();
      sh_tmp[tid] += t2;
      __syncthreads();
    }
    if (tid < A.nbScan) A.blocksums[tid] = sh_tmp[tid] - v;
    __syncthreads();
    int loc[4], s = 0;
#pragma unroll
    for (int k = 0; k < 4; ++k) { loc[k] = A.deg_hist[tid * 4 + k]; s += loc[k]; }
    __syncthreads();
    sh_tmp[tid] = s;
    __syncthreads();
    for (int off = 1; off < 256; off <<= 1) {
      int t2 = (tid >= off) ? sh_tmp[tid - off] : 0;
      __syncthreads();
      sh_tmp[tid] += t2;
      __syncthreads();
    }
    int run = sh_tmp[tid] - s;
#pragma unroll
    for (int k = 0; k < 4; ++k) { A.deg_cursor[tid * 4 + k] = run; run += loc[k]; }
  }
  grid.sync();

  // ---- P3: scanC over virtual blocks ----
  for (int vb = bid; vb < A.nbScan; vb += nb) {
    for (int b2 = tid; b2 < 1024; b2 += 256) sh_a[b2] = 0;
    __syncthreads();
    int i = vb * 256 + tid;
    int d2 = 0, lpos = 0;
    if (i < A.N) {
      int o = A.offsets[i] + A.blocksums[vb];
      A.offsets[i] = o;
      A.cursor[i] = o;
      d2 = min(A.deg[i], 1023);
      lpos = atomicAdd(&sh_a[d2], 1);
    }
    if (i == 0) A.offsets[A.N] = A.E;
    __syncthreads();
    for (int b2 = tid; b2 < 1024; b2 += 256) {
      int c = sh_a[b2];
      sh_b[b2] = c ? atomicAdd(&A.deg_cursor[b2], c) : 0;
    }
    __syncthreads();
    if (i < A.N) A.perm[sh_b[d2] + lpos] = i;
    __syncthreads();
  }
  grid.sync();

  // ---- P4: edge scatter + noise[hop1] + noise[hop2], mixed ----
  {
    int Zs = 2 * A.Zn;
    int T = A.nbHist + Zs;
    for (int u = bid; u < T; u += nb) {
      int w, nz;
      if (mix_role(u, T, Zs, &w, &nz)) {
        if (nz < A.Zn) gen_noise8(A.noise + NDl, NDl, nz, A.k0b, A.k1b);
        else gen_noise8(A.noise + 2 * NDl, NDl, nz - A.Zn, A.k0c, A.k1c);
      } else {
        int t = w * 256 + tid;
        if (t < A.E4) {
          int4 d4 = ((const int4*)A.dst)[t];
          int4 s4 = ((const int4*)A.src)[t];
          A.sorted_src[atomicAdd(&A.cursor[d4.x], 1)] = s4.x;
          A.sorted_src[atomicAdd(&A.cursor[d4.y], 1)] = s4.y;
          A.sorted_src[atomicAdd(&A.cursor[d4.z], 1)] = s4.z;
          A.sorted_src[atomicAdd(&A.cursor[d4.w], 1)] = s4.w;
        }
        int rem = A.E4 * 4 + t;
        if (t < A.E - A.E4 * 4) {
          int dd = A.dst[rem];
          A.sorted_src[atomicAdd(&A.cursor[dd], 1)] = A.src[rem];
        }
      }
    }
  }
  grid.sync();

  // ---- P5..P7: the three hops ----
  for (int u = bid; u < A.hopU; u += nb)
    hop_unit(u * 16 + (tid >> 4), A.out, A.mir0, A.out + NDl, A.mir1,
             A.offsets, A.sorted_src, A.perm, A.noise, A.N, A.E);
  grid.sync();
  for (int u = bid; u < A.hopU; u += nb)
    hop_unit(u * 16 + (tid >> 4), A.out + NDl, A.mir1, A.out + 2 * NDl, A.mir0,
             A.offsets, A.sorted_src, A.perm, A.noise + NDl, A.N, A.E);
  grid.sync();
  for (int u = bid; u < A.hopU; u += nb)
    hop_unit(u * 16 + (tid >> 4), A.out + 2 * NDl, A.mir0, A.out + 3 * NDl,
             (uint16_t*)nullptr, A.offsets, A.sorted_src, A.perm,
             A.noise + 2 * NDl, A.N, A.E);
}

// =================== FALLBACK PATH (round-3 proven kernels) =================
__global__ __launch_bounds__(256) void front_kernel(
    const int* __restrict__ dst, int* __restrict__ counts,
    int* __restrict__ deg_hist, int E4, int E,
    const float* __restrict__ xin, float* __restrict__ out0,
    uint16_t* __restrict__ mir, int N,
    float* __restrict__ noise0, int s, int Z, int nbHist,
    uint32_t k0, uint32_t k1) {
  int w, nz;
  if (Z > 0 && role_split(blockIdx.x, s, Z, &w, &nz)) {
    gen_noise8(noise0, (size_t)N * D, nz, k0, k1);
    return;
  }
  if (Z == 0) w = blockIdx.x;
  if (w < nbHist) {
    if (w == 0) {
      for (int bb = threadIdx.x; bb < 1024; bb += 256) deg_hist[bb] = 0;
    }
    int t = w * 256 + threadIdx.x;
    if (t < E4) {
      int4 d4 = ((const int4*)dst)[t];
      atomicAdd(&counts[d4.x], 1);
      atomicAdd(&counts[d4.y], 1);
      atomicAdd(&counts[d4.z], 1);
      atomicAdd(&counts[d4.w], 1);
    }
    int rem = E4 * 4 + t;
    if (t < E - E4 * 4) atomicAdd(&counts[dst[rem]], 1);
    return;
  }
  int t = (w - nbHist) * 256 + threadIdx.x;
  int row = t >> 6;
  int lane = t & 63;
  if (row >= N) return;
  size_t base = (size_t)row * D + 2 * lane;
  float2 v = *(const float2*)(xin + base);
  float ss = v.x * v.x + v.y * v.y;
#pragma unroll
  for (int off = 32; off > 0; off >>= 1) ss += __shfl_xor(ss, off);
  float denom = fmaxf(sqrtf(ss), 1e-12f);
  float2 o = make_float2(v.x / denom, v.y / denom);
  *(float2*)(out0 + base) = o;
  if (mir) {
    uint32_t wq = f32_to_bf16_rne(o.x) | (f32_to_bf16_rne(o.y) << 16);
    *(uint32_t*)(mir + base) = wq;
  }
}

__global__ __launch_bounds__(256) void scanA_kernel(
    int* __restrict__ counts, int* __restrict__ blocksums,
    int* __restrict__ deg, int* __restrict__ deg_hist, int N) {
  __shared__ int tmp[256];
  __shared__ int lhist[1024];
  for (int b = threadIdx.x; b < 1024; b += 256) lhist[b] = 0;
  int tid = threadIdx.x;
  int i = blockIdx.x * 256 + tid;
  int v = (i < N) ? counts[i] : 0;
  tmp[tid] = v;
  __syncthreads();
  if (i < N) {
    deg[i] = v;
    atomicAdd(&lhist[min(v, 1023)], 1);
  }
  for (int off = 1; off < 256; off <<= 1) {
    int t = (tid >= off) ? tmp[tid - off] : 0;
    __syncthreads();
    tmp[tid] += t;
    __syncthreads();
  }
  if (i < N) counts[i] = tmp[tid] - v;
  if (tid == 255) blocksums[blockIdx.x] = tmp[tid];
  __syncthreads();
  for (int b = threadIdx.x; b < 1024; b += 256) {
    int c = lhist[b];
    if (c) atomicAdd(&deg_hist[b], c);
  }
}

__global__ __launch_bounds__(256) void scanB_kernel(
    int* __restrict__ blocksums, int nb,
    const int* __restrict__ deg_hist, int* __restrict__ deg_cursor) {
  __shared__ int tmp[256];
  int tid = threadIdx.x;
  int v = (tid < nb) ? blocksums[tid] : 0;
  tmp[tid] = v;
  __syncthreads();
  for (int off = 1; off < 256; off <<= 1) {
    int t = (tid >= off) ? tmp[tid - off] : 0;
    __syncthreads();
    tmp[tid] += t;
    __syncthreads();
  }
  if (tid < nb) blocksums[tid] = tmp[tid] - v;
  __syncthreads();
  int loc[4], s = 0;
#pragma unroll
  for (int k = 0; k < 4; ++k) { loc[k] = deg_hist[tid * 4 + k]; s += loc[k]; }
  __syncthreads();
  tmp[tid] = s;
  __syncthreads();
  for (int off = 1; off < 256; off <<= 1) {
    int t = (tid >= off) ? tmp[tid - off] : 0;
    __syncthreads();
    tmp[tid] += t;
    __syncthreads();
  }
  int run = tmp[tid] - s;
#pragma unroll
  for (int k = 0; k < 4; ++k) { deg_cursor[tid * 4 + k] = run; run += loc[k]; }
}

__global__ __launch_bounds__(256) void scanC_kernel(
    int* __restrict__ offsets, int* __restrict__ cursor,
    const int* __restrict__ blocksums, const int* __restrict__ deg,
    int* __restrict__ deg_cursor, int* __restrict__ perm, int N, int E) {
  __shared__ int lhist[1024];
  __shared__ int lbase[1024];
  for (int b = threadIdx.x; b < 1024; b += 256) lhist[b] = 0;
  __syncthreads();
  int i = blockIdx.x * 256 + threadIdx.x;
  int d = 0, lpos = 0;
  if (i < N) {
    int o = offsets[i] + blocksums[blockIdx.x];
    offsets[i] = o;
    cursor[i] = o;
    d = min(deg[i], 1023);
    lpos = atomicAdd(&lhist[d], 1);
  }
  if (i == 0) offsets[N] = E;
  __syncthreads();
  for (int b = threadIdx.x; b < 1024; b += 256) {
    int c = lhist[b];
    lbase[b] = c ? atomicAdd(&deg_cursor[b], c) : 0;
  }
  __syncthreads();
  if (i < N) perm[lbase[d] + lpos] = i;
}

__global__ __launch_bounds__(256) void edgescatter4_kernel(
    const int* __restrict__ src, const int* __restrict__ dst,
    int* __restrict__ cursor, int* __restrict__ sorted_src, int E4, int E) {
  int t = blockIdx.x * blockDim.x + threadIdx.x;
  if (t < E4) {
    int4 d = ((const int4*)dst)[t];
    int4 s = ((const int4*)src)[t];
    sorted_src[atomicAdd(&cursor[d.x], 1)] = s.x;
    sorted_src[atomicAdd(&cursor[d.y], 1)] = s.y;
    sorted_src[atomicAdd(&cursor[d.z], 1)] = s.z;
    sorted_src[atomicAdd(&cursor[d.w], 1)] = s.w;
  }
  int rem = E4 * 4 + t;
  if (t < E - E4 * 4) {
    int d = dst[rem];
    sorted_src[atomicAdd(&cursor[d], 1)] = src[rem];
  }
}

__global__ __launch_bounds__(256, 4) void hop_kernel_bf16_pre(
    const float* __restrict__ hprev, const uint16_t* __restrict__ mprev,
    float* __restrict__ hout, uint16_t* __restrict__ mout,
    const int* __restrict__ offsets, const int* __restrict__ sorted_src,
    const int* __restrict__ perm, const float* __restrict__ noise,
    float* __restrict__ noiseNext, int s, int Z,
    uint32_t nk0, uint32_t nk1, int N, int E) {
  int w, nz;
  if (Z > 0 && role_split(blockIdx.x, s, Z, &w, &nz)) {
    gen_noise8(noiseNext, (size_t)N * D, nz, nk0, nk1);
    return;
  }
  if (Z == 0) w = blockIdx.x;
  hop_unit(w * 16 + (threadIdx.x >> 4), hprev, mprev, hout, mout,
           offsets, sorted_src, perm, noise, N, E);
}

// f32 fallback hop (no-workspace path)
union V16 { float4 v[4]; float f[16]; };

__global__ __launch_bounds__(256) void hop_kernel_f32(
    const float* __restrict__ hprev, float* __restrict__ hout,
    const int* __restrict__ offsets, const int* __restrict__ sorted_src,
    const int* __restrict__ perm, int N, uint32_t k0, uint32_t k1) {
  int g = (blockIdx.x * blockDim.x + threadIdx.x) >> 3;
  int sub = threadIdx.x & 7;
  if (g >= N) return;
  int r = perm[g];
  size_t rbase = (size_t)r * D + sub * 16;

  V16 b;
  {
    const float4* p = (const float4*)(hprev + rbase);
    b.v[0] = p[0]; b.v[1] = p[1]; b.v[2] = p[2]; b.v[3] = p[3];
  }
  V16 acc;
#pragma unroll
  for (int i = 0; i < 16; ++i) acc.f[i] = 0.f;

  int j = offsets[r], jhi = offsets[r + 1];
  V16 a;
  if (j < jhi) {
    const float4* p = (const float4*)(hprev + (size_t)sorted_src[j] * D + sub * 16);
    a.v[0] = p[0]; a.v[1] = p[1]; a.v[2] = p[2]; a.v[3] = p[3];
  }
  while (j < jhi) {
    int jn = j + 1;
    V16 an;
    if (jn < jhi) {
      const float4* p = (const float4*)(hprev + (size_t)sorted_src[jn] * D + sub * 16);
      an.v[0] = p[0]; an.v[1] = p[1]; an.v[2] = p[2]; an.v[3] = p[3];
    }
    float part = a.f[0] * b.f[0];
#pragma unroll
    for (int i = 1; i < 16; ++i) part = fmaf(a.f[i], b.f[i], part);
    part += __shfl_xor(part, 1);
    part += __shfl_xor(part, 2);
    part += __shfl_xor(part, 4);
    float alpha = 1.0f / (1.0f + expf(-part));
#pragma unroll
    for (int i = 0; i < 16; ++i) acc.f[i] = fmaf(alpha, a.f[i], acc.f[i]);
    a = an;
    j = jn;
  }

  uint32_t idx = (uint32_t)rbase;
  float ss = 0.f;
#pragma unroll
  for (int i = 0; i < 16; ++i) {
    acc.f[i] += 0.1f * jax_normal_elem(k0, k1, idx + (uint32_t)i);
    ss = fmaf(acc.f[i], acc.f[i], ss);
  }
  ss += __shfl_xor(ss, 1);
  ss += __shfl_xor(ss, 2);
  ss += __shfl_xor(ss, 4);
  float denom = fmaxf(sqrtf(ss), 1e-12f);
#pragma unroll
  for (int i = 0; i < 16; ++i) acc.f[i] = acc.f[i] / denom;
  {
    float4* p = (float4*)(hout + rbase);
    p[0] = acc.v[0]; p[1] = acc.v[1]; p[2] = acc.v[2]; p[3] = acc.v[3];
  }
}

// ============================ host launcher =================================
extern "C" void kernel_launch(void* const* d_in, const int* in_sizes, int n_in,
                              void* d_out, int out_size, void* d_ws, size_t ws_size,
                              hipStream_t stream) {
  const float* x = (const float*)d_in[0];
  const int* ei = (const int*)d_in[1];
  int N = in_sizes[0] / D;   // 50000
  int E = in_sizes[1] / 2;   // 800000
  const int* src = ei;
  const int* dst = ei + E;
  float* out = (float*)d_out;
  size_t ND = (size_t)N * D;

  int nblocksN = (N + 255) / 256;

  int* offsets = (int*)d_ws;
  int* cursor = offsets + (N + 1);
  int* perm = cursor + N;
  int* deg = perm + N;
  int* deg_hist = deg + N;
  int* deg_cursor = deg_hist + 1024;
  int* blocksums = deg_cursor + 1024;
  int* sorted_src = blocksums + 256;
  size_t intWords = (size_t)(N + 1) + N + N + N + 1024 + 1024 + 256 + E;
  size_t mirOff = (intWords * 4 + 255) & ~(size_t)255;
  size_t needMir = mirOff + 2 * ND * sizeof(uint16_t);
  bool use_bf16 = ws_size >= needMir;
  uint16_t* mir0 = (uint16_t*)((char*)d_ws + mirOff);
  uint16_t* mir1 = mir0 + ND;
  size_t noiseOff = needMir;
  size_t needNoise = noiseOff + 3 * ND * sizeof(float);
  bool use_noise = use_bf16 && ws_size >= needNoise;
  float* noisebuf = (float*)((char*)d_ws + noiseOff);

  uint32_t nk0[3], nk1[3];
  for (int k = 0; k < 3; ++k)
    threefry2x32(0u, 1u, 0u, (uint32_t)k, &nk0[k], &nk1[k]);

  int E4 = E / 4;
  int e4Blocks = (max(E4, E - E4 * 4) + 255) / 256;
  int rowWaveBlocks = (int)(((size_t)N * 64 + 255) / 256);
  int hopBlocks16 = (int)(((size_t)N * 16 + 255) / 256);
  int hopBlocks8 = (int)(((size_t)N * 8 + 255) / 256);
  int Zn = use_noise ? (int)((ND + 2047) / 2048) : 0;

  // ---- cooperative capability (queried once; host-only, capture-safe) ----
  static int s_nb = -2;
  if (s_nb == -2) {
    s_nb = -1;
    int devId = 0;
    if (hipGetDevice(&devId) == hipSuccess) {
      hipDeviceProp_t prop;
      if (hipGetDeviceProperties(&prop, devId) == hipSuccess &&
          prop.cooperativeLaunch) {
        int maxB = 0;
        if (hipOccupancyMaxActiveBlocksPerMultiprocessor(&maxB, mega_kernel,
                                                         256, 0) == hipSuccess &&
            maxB > 0) {
          long long g = (long long)maxB * prop.multiProcessorCount;
          s_nb = (int)(g > 4096 ? 4096 : g);
        }
      }
    }
  }

  bool try_mega = use_noise && nblocksN <= 256 && s_nb > 0;
  if (try_mega) {
    MegaArgs A;
    A.x = x; A.src = src; A.dst = dst; A.out = out;
    A.offsets = offsets; A.cursor = cursor; A.perm = perm; A.deg = deg;
    A.deg_hist = deg_hist; A.deg_cursor = deg_cursor; A.blocksums = blocksums;
    A.sorted_src = sorted_src; A.mir0 = mir0; A.mir1 = mir1; A.noise = noisebuf;
    A.N = N; A.E = E; A.E4 = E4; A.nbHist = e4Blocks; A.nbNorm = rowWaveBlocks;
    A.nbScan = nblocksN; A.Zn = Zn; A.hopU = (N + 15) / 16;
    A.k0a = nk0[0]; A.k1a = nk1[0];
    A.k0b = nk0[1]; A.k1b = nk1[1];
    A.k0c = nk0[2]; A.k1c = nk1[2];
    void* args[] = { &A };
    hipError_t cerr = hipLaunchCooperativeKernel(mega_kernel, dim3(s_nb),
                                                 dim3(256), args, 0, stream);
    if (cerr == hipSuccess) return;
    // fall through to the multi-kernel path on failure
  }

  // -------------------- fallback: round-3 proven path -----------------------
  int nbHist = e4Blocks;
  int nbNorm = rowWaveBlocks;
  int WF = nbHist + nbNorm;
  int TF = WF + Zn;
  int sF = Zn ? max(2, TF / Zn) : 1;
  hipMemsetAsync(offsets, 0, (size_t)(N + 1) * sizeof(int), stream);
  hipLaunchKernelGGL(front_kernel, dim3(Zn ? TF : WF), dim3(256), 0, stream,
                     dst, offsets, deg_hist, E4, E,
                     x, out, use_bf16 ? mir0 : (uint16_t*)nullptr, N,
                     noisebuf, sF, Zn, nbHist, nk0[0], nk1[0]);
  hipLaunchKernelGGL(scanA_kernel, dim3(nblocksN), dim3(256), 0, stream,
                     offsets, blocksums, deg, deg_hist, N);
  hipLaunchKernelGGL(scanB_kernel, dim3(1), dim3(256), 0, stream,
                     blocksums, nblocksN, deg_hist, deg_cursor);
  hipLaunchKernelGGL(scanC_kernel, dim3(nblocksN), dim3(256), 0, stream,
                     offsets, cursor, blocksums, deg, deg_cursor, perm, N, E);
  hipLaunchKernelGGL(edgescatter4_kernel, dim3(e4Blocks), dim3(256), 0, stream,
                     src, dst, cursor, sorted_src, E4, E);

  if (use_bf16 && use_noise) {
    uint16_t* mirs[4] = {mir0, mir1, mir0, nullptr};
    for (int k = 0; k < 3; ++k) {
      const float* hk = out + (size_t)k * ND;
      float* hk1 = out + (size_t)(k + 1) * ND;
      int ZH = (k < 2) ? Zn : 0;
      int TH = hopBlocks16 + ZH;
      int sH = ZH ? max(2, TH / ZH) : 1;
      float* nNext = (k < 2) ? (noisebuf + (size_t)(k + 1) * ND) : nullptr;
      uint32_t kn0 = (k < 2) ? nk0[k + 1] : 0u;
      uint32_t kn1 = (k < 2) ? nk1[k + 1] : 0u;
      hipLaunchKernelGGL(hop_kernel_bf16_pre, dim3(ZH ? TH : hopBlocks16),
                         dim3(256), 0, stream, hk, mirs[k], hk1, mirs[k + 1],
                         offsets, sorted_src, perm,
                         noisebuf + (size_t)k * ND, nNext, sH, ZH,
                         kn0, kn1, N, E);
    }
  } else {
    for (int k = 0; k < 3; ++k) {
      const float* hk = out + (size_t)k * ND;
      float* hk1 = out + (size_t)(k + 1) * ND;
      hipLaunchKernelGGL(hop_kernel_f32, dim3(hopBlocks8), dim3(256), 0, stream,
                         hk, hk1, offsets, sorted_src, perm, N, nk0[k], nk1[k]);
    }
  }
}

// Round 5
// 347.621 us; speedup vs baseline: 3.7649x; 3.7649x over previous
//
#include <hip/hip_runtime.h>
#include <cstdint>
#include <cstddef>

#define D 128

typedef float v2f __attribute__((ext_vector_type(2)));

// ---------------- Threefry-2x32 (JAX/Random123), host+device ----------------
__host__ __device__ inline uint32_t rotl32(uint32_t v, int d) {
  return (v << d) | (v >> (32 - d));
}

__host__ __device__ inline void threefry2x32(uint32_t k0, uint32_t k1,
                                             uint32_t x0, uint32_t x1,
                                             uint32_t* o0, uint32_t* o1) {
  uint32_t k2 = k0 ^ k1 ^ 0x1BD11BDAu;
  x0 += k0; x1 += k1;
#define TF_RND(r) x0 += x1; x1 = rotl32(x1, (r)); x1 ^= x0;
  TF_RND(13) TF_RND(15) TF_RND(26) TF_RND(6)
  x0 += k1; x1 += k2 + 1u;
  TF_RND(17) TF_RND(29) TF_RND(16) TF_RND(24)
  x0 += k2; x1 += k0 + 2u;
  TF_RND(13) TF_RND(15) TF_RND(26) TF_RND(6)
  x0 += k0; x1 += k1 + 3u;
  TF_RND(17) TF_RND(29) TF_RND(16) TF_RND(24)
  x0 += k1; x1 += k2 + 4u;
  TF_RND(13) TF_RND(15) TF_RND(26) TF_RND(6)
  x0 += k2; x1 += k0 + 5u;
#undef TF_RND
  *o0 = x0; *o1 = x1;
}

// XLA ErfInv32 (Giles) — full-precision variant (kept for f32 fallback path).
__device__ inline float erfinv_f32(float x) {
  float w = -log1pf(-x * x);
  float p;
  if (w < 5.0f) {
    w = w - 2.5f;
    p = 2.81022636e-08f;
    p = fmaf(p, w, 3.43273939e-07f);
    p = fmaf(p, w, -3.5233877e-06f);
    p = fmaf(p, w, -4.39150654e-06f);
    p = fmaf(p, w, 0.00021858087f);
    p = fmaf(p, w, -0.00125372503f);
    p = fmaf(p, w, -0.00417768164f);
    p = fmaf(p, w, 0.246640727f);
    p = fmaf(p, w, 1.50140941f);
  } else {
    w = sqrtf(w) - 3.0f;
    p = -0.000200214257f;
    p = fmaf(p, w, 0.000100950558f);
    p = fmaf(p, w, 0.00134934322f);
    p = fmaf(p, w, -0.00367342844f);
    p = fmaf(p, w, 0.00573950773f);
    p = fmaf(p, w, -0.0076224613f);
    p = fmaf(p, w, 0.00943887047f);
    p = fmaf(p, w, 1.00167406f);
    p = fmaf(p, w, 2.83297682f);
  }
  return p * x;
}

// Fast erfinv: same Giles polynomials, w = -ln(1-x^2) via exact-FMA + v_log.
// |δnoise| ~1e-7 << tolerance (bench-verified passing in rounds 2-3).
__device__ inline float erfinv_fast(float x) {
  float t = fmaf(-x, x, 1.0f);
  float w = -0.693147180559945f * __builtin_amdgcn_logf(t);
  float p;
  if (__builtin_expect(w < 5.0f, 1)) {
    w = w - 2.5f;
    p = 2.81022636e-08f;
    p = fmaf(p, w, 3.43273939e-07f);
    p = fmaf(p, w, -3.5233877e-06f);
    p = fmaf(p, w, -4.39150654e-06f);
    p = fmaf(p, w, 0.00021858087f);
    p = fmaf(p, w, -0.00125372503f);
    p = fmaf(p, w, -0.00417768164f);
    p = fmaf(p, w, 0.246640727f);
    p = fmaf(p, w, 1.50140941f);
  } else {
    w = __builtin_amdgcn_sqrtf(w) - 3.0f;
    p = -0.000200214257f;
    p = fmaf(p, w, 0.000100950558f);
    p = fmaf(p, w, 0.00134934322f);
    p = fmaf(p, w, -0.00367342844f);
    p = fmaf(p, w, 0.00573950773f);
    p = fmaf(p, w, -0.0076224613f);
    p = fmaf(p, w, 0.00943887047f);
    p = fmaf(p, w, 1.00167406f);
    p = fmaf(p, w, 2.83297682f);
  }
  return p * x;
}

__device__ inline float jax_normal_elem(uint32_t k0, uint32_t k1, uint32_t idx) {
  uint32_t o0, o1;
  threefry2x32(k0, k1, 0u, idx, &o0, &o1);
  uint32_t bits = o0 ^ o1;
  float f = __uint_as_float((bits >> 9) | 0x3F800000u) - 1.0f;
  float u = f * 2.0f + (-0.99999994f);
  u = fmaxf(-0.99999994f, u);
  return 1.41421356237309505f * erfinv_f32(u);
}

__device__ inline float jax_normal_fast(uint32_t k0, uint32_t k1, uint32_t idx) {
  uint32_t o0, o1;
  threefry2x32(k0, k1, 0u, idx, &o0, &o1);
  uint32_t bits = o0 ^ o1;
  float f = __uint_as_float((bits >> 9) | 0x3F800000u) - 1.0f;
  float u = f * 2.0f + (-0.99999994f);
  u = fmaxf(-0.99999994f, u);
  return 1.41421356237309505f * erfinv_fast(u);
}

__device__ inline uint32_t f32_to_bf16_rne(float f) {
  uint32_t u = __float_as_uint(f);
  u += 0x7fffu + ((u >> 16) & 1u);
  return u >> 16;
}

// ---------------- Front kernel: hist4 | norm(out0 + bf16 mirror) ------------
__global__ __launch_bounds__(256) void front_kernel(
    const int* __restrict__ dst, int* __restrict__ counts,
    int* __restrict__ deg_hist, int E4, int E,
    const float* __restrict__ xin, float* __restrict__ out0,
    uint16_t* __restrict__ mir, int N, int nbHist) {
  int w = blockIdx.x;
  if (w < nbHist) {
    if (w == 0) {
      for (int bb = threadIdx.x; bb < 1024; bb += 256) deg_hist[bb] = 0;
    }
    int t = w * 256 + threadIdx.x;
    if (t < E4) {
      int4 d4 = ((const int4*)dst)[t];
      atomicAdd(&counts[d4.x], 1);
      atomicAdd(&counts[d4.y], 1);
      atomicAdd(&counts[d4.z], 1);
      atomicAdd(&counts[d4.w], 1);
    }
    int rem = E4 * 4 + t;
    if (t < E - E4 * 4) atomicAdd(&counts[dst[rem]], 1);
    return;
  }
  int t = (w - nbHist) * 256 + threadIdx.x;
  int row = t >> 6;
  int lane = t & 63;
  if (row >= N) return;
  size_t base = (size_t)row * D + 2 * lane;
  float2 v = *(const float2*)(xin + base);
  float ss = v.x * v.x + v.y * v.y;
#pragma unroll
  for (int off = 32; off > 0; off >>= 1) ss += __shfl_xor(ss, off);
  float denom = fmaxf(sqrtf(ss), 1e-12f);
  float2 o = make_float2(v.x / denom, v.y / denom);
  *(float2*)(out0 + base) = o;
  if (mir) {
    uint32_t wq = f32_to_bf16_rne(o.x) | (f32_to_bf16_rne(o.y) << 16);
    *(uint32_t*)(mir + base) = wq;
  }
}

// ---------------- CSR build (scans + scatter) -------------------------------
__global__ __launch_bounds__(256) void scanA_kernel(
    int* __restrict__ counts, int* __restrict__ blocksums,
    int* __restrict__ deg, int* __restrict__ deg_hist, int N) {
  __shared__ int tmp[256];
  __shared__ int lhist[1024];
  for (int b = threadIdx.x; b < 1024; b += 256) lhist[b] = 0;
  int tid = threadIdx.x;
  int i = blockIdx.x * 256 + tid;
  int v = (i < N) ? counts[i] : 0;
  tmp[tid] = v;
  __syncthreads();
  if (i < N) {
    deg[i] = v;
    atomicAdd(&lhist[min(v, 1023)], 1);
  }
  for (int off = 1; off < 256; off <<= 1) {
    int t = (tid >= off) ? tmp[tid - off] : 0;
    __syncthreads();
    tmp[tid] += t;
    __syncthreads();
  }
  if (i < N) counts[i] = tmp[tid] - v;  // exclusive
  if (tid == 255) blocksums[blockIdx.x] = tmp[tid];
  __syncthreads();
  for (int b = threadIdx.x; b < 1024; b += 256) {
    int c = lhist[b];
    if (c) atomicAdd(&deg_hist[b], c);
  }
}

__global__ __launch_bounds__(256) void scanB_kernel(
    int* __restrict__ blocksums, int nb,
    const int* __restrict__ deg_hist, int* __restrict__ deg_cursor) {
  __shared__ int tmp[256];
  int tid = threadIdx.x;
  int v = (tid < nb) ? blocksums[tid] : 0;
  tmp[tid] = v;
  __syncthreads();
  for (int off = 1; off < 256; off <<= 1) {
    int t = (tid >= off) ? tmp[tid - off] : 0;
    __syncthreads();
    tmp[tid] += t;
    __syncthreads();
  }
  if (tid < nb) blocksums[tid] = tmp[tid] - v;
  __syncthreads();
  int loc[4], s = 0;
#pragma unroll
  for (int k = 0; k < 4; ++k) { loc[k] = deg_hist[tid * 4 + k]; s += loc[k]; }
  __syncthreads();
  tmp[tid] = s;
  __syncthreads();
  for (int off = 1; off < 256; off <<= 1) {
    int t = (tid >= off) ? tmp[tid - off] : 0;
    __syncthreads();
    tmp[tid] += t;
    __syncthreads();
  }
  int run = tmp[tid] - s;
#pragma unroll
  for (int k = 0; k < 4; ++k) { deg_cursor[tid * 4 + k] = run; run += loc[k]; }
}

__global__ __launch_bounds__(256) void scanC_kernel(
    int* __restrict__ offsets, int* __restrict__ cursor,
    const int* __restrict__ blocksums, const int* __restrict__ deg,
    int* __restrict__ deg_cursor, int* __restrict__ perm, int N, int E) {
  __shared__ int lhist[1024];
  __shared__ int lbase[1024];
  for (int b = threadIdx.x; b < 1024; b += 256) lhist[b] = 0;
  __syncthreads();
  int i = blockIdx.x * 256 + threadIdx.x;
  int d = 0, lpos = 0;
  if (i < N) {
    int o = offsets[i] + blocksums[blockIdx.x];
    offsets[i] = o;
    cursor[i] = o;
    d = min(deg[i], 1023);
    lpos = atomicAdd(&lhist[d], 1);
  }
  if (i == 0) offsets[N] = E;
  __syncthreads();
  for (int b = threadIdx.x; b < 1024; b += 256) {
    int c = lhist[b];
    lbase[b] = c ? atomicAdd(&deg_cursor[b], c) : 0;
  }
  __syncthreads();
  if (i < N) perm[lbase[d] + lpos] = i;
}

__global__ __launch_bounds__(256) void edgescatter4_kernel(
    const int* __restrict__ src, const int* __restrict__ dst,
    int* __restrict__ cursor, int* __restrict__ sorted_src, int E4, int E) {
  int t = blockIdx.x * blockDim.x + threadIdx.x;
  if (t < E4) {
    int4 d = ((const int4*)dst)[t];
    int4 s = ((const int4*)src)[t];
    sorted_src[atomicAdd(&cursor[d.x], 1)] = s.x;
    sorted_src[atomicAdd(&cursor[d.y], 1)] = s.y;
    sorted_src[atomicAdd(&cursor[d.z], 1)] = s.z;
    sorted_src[atomicAdd(&cursor[d.w], 1)] = s.w;
  }
  int rem = E4 * 4 + t;
  if (t < E - E4 * 4) {
    int d = dst[rem];
    sorted_src[atomicAdd(&cursor[d], 1)] = src[rem];
  }
}

// ---------------- Fused hop (bf16 gather): 16 lanes/row, 4 rows/wave --------
// Inline fast RNG in the epilogue — measured FREE under gather latency
// (round 0 vs round 3: hop with/without RNG both 65 µs at 16 waves/CU).
// __launch_bounds__(256,8): 32 waves/CU — gather is latency-bound; doubling
// resident waves doubles outstanding gathers. VGPR must stay <=64.
union V8 { float4 v[2]; v2f d[4]; float f[8]; };
union U4B { uint4 v; uint32_t u[4]; };

__device__ inline void hop_edge_pk(const U4B& raw, const V8& b, V8& acc) {
  V8 af;
#pragma unroll
  for (int i = 0; i < 4; ++i) {
    af.f[2 * i] = __uint_as_float(raw.u[i] << 16);
    af.f[2 * i + 1] = __uint_as_float(raw.u[i] & 0xffff0000u);
  }
  v2f p2 = af.d[0] * b.d[0];
#pragma unroll
  for (int q = 1; q < 4; ++q) p2 = __builtin_elementwise_fma(af.d[q], b.d[q], p2);
  float part = p2.x + p2.y;
  part += __shfl_xor(part, 1);
  part += __shfl_xor(part, 2);
  part += __shfl_xor(part, 4);
  part += __shfl_xor(part, 8);
  float alpha = __builtin_amdgcn_rcpf(1.0f + __expf(-part));
  v2f av = { alpha, alpha };
#pragma unroll
  for (int q = 0; q < 4; ++q) acc.d[q] = __builtin_elementwise_fma(av, af.d[q], acc.d[q]);
}

__global__ __launch_bounds__(256, 8) void hop_kernel_bf16(
    const float* __restrict__ hprev, const uint16_t* __restrict__ mprev,
    float* __restrict__ hout, uint16_t* __restrict__ mout,
    const int* __restrict__ offsets, const int* __restrict__ sorted_src,
    const int* __restrict__ perm, int N, int E, uint32_t k0, uint32_t k1) {
  int g = (blockIdx.x * blockDim.x + threadIdx.x) >> 4;
  int sub = threadIdx.x & 15;
  if (g >= N) return;
  int r = perm[g];
  size_t rbase = (size_t)r * D + sub * 8;

  V8 b;
  {
    const float4* p = (const float4*)(hprev + rbase);
    b.v[0] = p[0]; b.v[1] = p[1];
  }
  V8 acc;
#pragma unroll
  for (int i = 0; i < 8; ++i) acc.f[i] = 0.f;

  int j0 = offsets[r];
  int cnt = offsets[r + 1] - j0;
  int Em1 = E - 1;
  const char* mb = (const char*)mprev + (uint32_t)(sub * 16);

  U4B buf[4];
  int sNext[4];
#pragma unroll
  for (int q = 0; q < 4; ++q) {
    uint32_t s = (uint32_t)sorted_src[min(j0 + q, Em1)];
    buf[q].v = *(const uint4*)(mb + (s << 8));
  }
#pragma unroll
  for (int q = 0; q < 4; ++q) sNext[q] = sorted_src[min(j0 + 4 + q, Em1)];

  int cnt4 = cnt & ~3;
  for (int i = 0; i < cnt4; i += 4) {
#pragma unroll
    for (int q = 0; q < 4; ++q) {
      hop_edge_pk(buf[q], b, acc);                                 // row i+q
      buf[q].v = *(const uint4*)(mb + ((uint32_t)sNext[q] << 8));  // row i+4+q
      sNext[q] = sorted_src[min(j0 + i + 8 + q, Em1)];             // row i+8+q
    }
  }
  int rem = cnt - cnt4;
#pragma unroll
  for (int q = 0; q < 3; ++q)
    if (q < rem) hop_edge_pk(buf[q], b, acc);

  // inline noise (bit-exact jax.random.normal, fast-log variant) + normalize
  uint32_t idx = (uint32_t)rbase;
  float ss = 0.f;
#pragma unroll
  for (int i2 = 0; i2 < 8; ++i2) {
    acc.f[i2] += 0.1f * jax_normal_fast(k0, k1, idx + (uint32_t)i2);
    ss = fmaf(acc.f[i2], acc.f[i2], ss);
  }
  ss += __shfl_xor(ss, 1);
  ss += __shfl_xor(ss, 2);
  ss += __shfl_xor(ss, 4);
  ss += __shfl_xor(ss, 8);
  float denom = fmaxf(sqrtf(ss), 1e-12f);
  float inv = __builtin_amdgcn_rcpf(denom);
  inv = inv * fmaf(-denom, inv, 2.0f);  // one NR step -> ~0.5 ulp
#pragma unroll
  for (int i2 = 0; i2 < 8; ++i2) acc.f[i2] *= inv;
  {
    float4* p = (float4*)(hout + rbase);
    p[0] = acc.v[0]; p[1] = acc.v[1];
  }
  if (mout) {
    U4B wq;
#pragma unroll
    for (int i2 = 0; i2 < 4; ++i2)
      wq.u[i2] = f32_to_bf16_rne(acc.f[2 * i2]) |
                 (f32_to_bf16_rne(acc.f[2 * i2 + 1]) << 16);
    *(uint4*)(mout + rbase) = wq.v;
  }
}

// ---------------- Fallback hop (f32 gather, no-workspace path) --------------
union V16 { float4 v[4]; float f[16]; };

__global__ __launch_bounds__(256) void hop_kernel_f32(
    const float* __restrict__ hprev, float* __restrict__ hout,
    const int* __restrict__ offsets, const int* __restrict__ sorted_src,
    const int* __restrict__ perm, int N, uint32_t k0, uint32_t k1) {
  int g = (blockIdx.x * blockDim.x + threadIdx.x) >> 3;
  int sub = threadIdx.x & 7;
  if (g >= N) return;
  int r = perm[g];
  size_t rbase = (size_t)r * D + sub * 16;

  V16 b;
  {
    const float4* p = (const float4*)(hprev + rbase);
    b.v[0] = p[0]; b.v[1] = p[1]; b.v[2] = p[2]; b.v[3] = p[3];
  }
  V16 acc;
#pragma unroll
  for (int i = 0; i < 16; ++i) acc.f[i] = 0.f;

  int j = offsets[r], jhi = offsets[r + 1];
  V16 a;
  if (j < jhi) {
    const float4* p = (const float4*)(hprev + (size_t)sorted_src[j] * D + sub * 16);
    a.v[0] = p[0]; a.v[1] = p[1]; a.v[2] = p[2]; a.v[3] = p[3];
  }
  while (j < jhi) {
    int jn = j + 1;
    V16 an;
    if (jn < jhi) {
      const float4* p = (const float4*)(hprev + (size_t)sorted_src[jn] * D + sub * 16);
      an.v[0] = p[0]; an.v[1] = p[1]; an.v[2] = p[2]; an.v[3] = p[3];
    }
    float part = a.f[0] * b.f[0];
#pragma unroll
    for (int i = 1; i < 16; ++i) part = fmaf(a.f[i], b.f[i], part);
    part += __shfl_xor(part, 1);
    part += __shfl_xor(part, 2);
    part += __shfl_xor(part, 4);
    float alpha = 1.0f / (1.0f + expf(-part));
#pragma unroll
    for (int i = 0; i < 16; ++i) acc.f[i] = fmaf(alpha, a.f[i], acc.f[i]);
    a = an;
    j = jn;
  }

  uint32_t idx = (uint32_t)rbase;
  float ss = 0.f;
#pragma unroll
  for (int i = 0; i < 16; ++i) {
    acc.f[i] += 0.1f * jax_normal_elem(k0, k1, idx + (uint32_t)i);
    ss = fmaf(acc.f[i], acc.f[i], ss);
  }
  ss += __shfl_xor(ss, 1);
  ss += __shfl_xor(ss, 2);
  ss += __shfl_xor(ss, 4);
  float denom = fmaxf(sqrtf(ss), 1e-12f);
#pragma unroll
  for (int i = 0; i < 16; ++i) acc.f[i] = acc.f[i] / denom;
  {
    float4* p = (float4*)(hout + rbase);
    p[0] = acc.v[0]; p[1] = acc.v[1]; p[2] = acc.v[2]; p[3] = acc.v[3];
  }
}

// ============================ host launcher =================================
extern "C" void kernel_launch(void* const* d_in, const int* in_sizes, int n_in,
                              void* d_out, int out_size, void* d_ws, size_t ws_size,
                              hipStream_t stream) {
  const float* x = (const float*)d_in[0];
  const int* ei = (const int*)d_in[1];
  int N = in_sizes[0] / D;   // 50000
  int E = in_sizes[1] / 2;   // 800000
  const int* src = ei;
  const int* dst = ei + E;
  float* out = (float*)d_out;
  size_t ND = (size_t)N * D;

  int nblocksN = (N + 255) / 256;

  // ws layout (ints): offsets[N+1] | cursor[N] | perm[N] | deg[N]
  //                 | deg_hist[1024] | deg_cursor[1024] | blocksums[256]
  //                 | sorted_src[E]
  //   then (256B aligned): bf16 mirrors mir0[N*D], mir1[N*D]
  int* offsets = (int*)d_ws;
  int* cursor = offsets + (N + 1);
  int* perm = cursor + N;
  int* deg = perm + N;
  int* deg_hist = deg + N;
  int* deg_cursor = deg_hist + 1024;
  int* blocksums = deg_cursor + 1024;
  int* sorted_src = blocksums + 256;
  size_t intWords = (size_t)(N + 1) + N + N + N + 1024 + 1024 + 256 + E;
  size_t mirOff = (intWords * 4 + 255) & ~(size_t)255;
  size_t needMir = mirOff + 2 * ND * sizeof(uint16_t);
  bool use_bf16 = ws_size >= needMir;
  uint16_t* mir0 = (uint16_t*)((char*)d_ws + mirOff);
  uint16_t* mir1 = mir0 + ND;

  // noise_keys = jax.random.split(jax.random.key(1), 3)
  uint32_t nk0[3], nk1[3];
  for (int k = 0; k < 3; ++k)
    threefry2x32(0u, 1u, 0u, (uint32_t)k, &nk0[k], &nk1[k]);

  int E4 = E / 4;
  int e4Blocks = (max(E4, E - E4 * 4) + 255) / 256;
  int rowWaveBlocks = (int)(((size_t)N * 64 + 255) / 256);  // 1 wave/row (norm)
  int hopBlocks16 = (int)(((size_t)N * 16 + 255) / 256);    // 16 lanes/row
  int hopBlocks8 = (int)(((size_t)N * 8 + 255) / 256);      // 8 lanes/row

  // ---- front: hist + norm(+mirror) fused ----
  hipMemsetAsync(offsets, 0, (size_t)(N + 1) * sizeof(int), stream);
  hipLaunchKernelGGL(front_kernel, dim3(e4Blocks + rowWaveBlocks), dim3(256), 0,
                     stream, dst, offsets, deg_hist, E4, E,
                     x, out, use_bf16 ? mir0 : (uint16_t*)nullptr, N, e4Blocks);
  hipLaunchKernelGGL(scanA_kernel, dim3(nblocksN), dim3(256), 0, stream,
                     offsets, blocksums, deg, deg_hist, N);
  hipLaunchKernelGGL(scanB_kernel, dim3(1), dim3(256), 0, stream,
                     blocksums, nblocksN, deg_hist, deg_cursor);
  hipLaunchKernelGGL(scanC_kernel, dim3(nblocksN), dim3(256), 0, stream,
                     offsets, cursor, blocksums, deg, deg_cursor, perm, N, E);
  hipLaunchKernelGGL(edgescatter4_kernel, dim3(e4Blocks), dim3(256), 0, stream,
                     src, dst, cursor, sorted_src, E4, E);

  if (use_bf16) {
    uint16_t* mirs[4] = {mir0, mir1, mir0, nullptr};  // last hop: no mirror out
    for (int k = 0; k < 3; ++k) {
      const float* hk = out + (size_t)k * ND;
      float* hk1 = out + (size_t)(k + 1) * ND;
      hipLaunchKernelGGL(hop_kernel_bf16, dim3(hopBlocks16), dim3(256), 0,
                         stream, hk, mirs[k], hk1, mirs[k + 1], offsets,
                         sorted_src, perm, N, E, nk0[k], nk1[k]);
    }
  } else {
    for (int k = 0; k < 3; ++k) {
      const float* hk = out + (size_t)k * ND;
      float* hk1 = out + (size_t)(k + 1) * ND;
      hipLaunchKernelGGL(hop_kernel_f32, dim3(hopBlocks8), dim3(256), 0, stream,
                         hk, hk1, offsets, sorted_src, perm, N, nk0[k], nk1[k]);
    }
  }
}

// Round 7
// 338.866 us; speedup vs baseline: 3.8621x; 1.0258x over previous
//
#include <hip/hip_runtime.h>
#include <cstdint>
#include <cstddef>

#define D 128

typedef float v2f __attribute__((ext_vector_type(2)));

// ---------------- Threefry-2x32 (JAX/Random123), host+device ----------------
__host__ __device__ inline uint32_t rotl32(uint32_t v, int d) {
  return (v << d) | (v >> (32 - d));
}

__host__ __device__ inline void threefry2x32(uint32_t k0, uint32_t k1,
                                             uint32_t x0, uint32_t x1,
                                             uint32_t* o0, uint32_t* o1) {
  uint32_t k2 = k0 ^ k1 ^ 0x1BD11BDAu;
  x0 += k0; x1 += k1;
#define TF_RND(r) x0 += x1; x1 = rotl32(x1, (r)); x1 ^= x0;
  TF_RND(13) TF_RND(15) TF_RND(26) TF_RND(6)
  x0 += k1; x1 += k2 + 1u;
  TF_RND(17) TF_RND(29) TF_RND(16) TF_RND(24)
  x0 += k2; x1 += k0 + 2u;
  TF_RND(13) TF_RND(15) TF_RND(26) TF_RND(6)
  x0 += k0; x1 += k1 + 3u;
  TF_RND(17) TF_RND(29) TF_RND(16) TF_RND(24)
  x0 += k1; x1 += k2 + 4u;
  TF_RND(13) TF_RND(15) TF_RND(26) TF_RND(6)
  x0 += k2; x1 += k0 + 5u;
#undef TF_RND
  *o0 = x0; *o1 = x1;
}

// XLA ErfInv32 (Giles) — full-precision variant (kept for f32 fallback path).
__device__ inline float erfinv_f32(float x) {
  float w = -log1pf(-x * x);
  float p;
  if (w < 5.0f) {
    w = w - 2.5f;
    p = 2.81022636e-08f;
    p = fmaf(p, w, 3.43273939e-07f);
    p = fmaf(p, w, -3.5233877e-06f);
    p = fmaf(p, w, -4.39150654e-06f);
    p = fmaf(p, w, 0.00021858087f);
    p = fmaf(p, w, -0.00125372503f);
    p = fmaf(p, w, -0.00417768164f);
    p = fmaf(p, w, 0.246640727f);
    p = fmaf(p, w, 1.50140941f);
  } else {
    w = sqrtf(w) - 3.0f;
    p = -0.000200214257f;
    p = fmaf(p, w, 0.000100950558f);
    p = fmaf(p, w, 0.00134934322f);
    p = fmaf(p, w, -0.00367342844f);
    p = fmaf(p, w, 0.00573950773f);
    p = fmaf(p, w, -0.0076224613f);
    p = fmaf(p, w, 0.00943887047f);
    p = fmaf(p, w, 1.00167406f);
    p = fmaf(p, w, 2.83297682f);
  }
  return p * x;
}

// Fast erfinv: same Giles polynomials, w = -ln(1-x^2) via exact-FMA + v_log.
// |δnoise| ~1e-7 << tolerance (bench-verified passing rounds 2-3, 5).
__device__ inline float erfinv_fast(float x) {
  float t = fmaf(-x, x, 1.0f);
  float w = -0.693147180559945f * __builtin_amdgcn_logf(t);
  float p;
  if (__builtin_expect(w < 5.0f, 1)) {
    w = w - 2.5f;
    p = 2.81022636e-08f;
    p = fmaf(p, w, 3.43273939e-07f);
    p = fmaf(p, w, -3.5233877e-06f);
    p = fmaf(p, w, -4.39150654e-06f);
    p = fmaf(p, w, 0.00021858087f);
    p = fmaf(p, w, -0.00125372503f);
    p = fmaf(p, w, -0.00417768164f);
    p = fmaf(p, w, 0.246640727f);
    p = fmaf(p, w, 1.50140941f);
  } else {
    w = __builtin_amdgcn_sqrtf(w) - 3.0f;
    p = -0.000200214257f;
    p = fmaf(p, w, 0.000100950558f);
    p = fmaf(p, w, 0.00134934322f);
    p = fmaf(p, w, -0.00367342844f);
    p = fmaf(p, w, 0.00573950773f);
    p = fmaf(p, w, -0.0076224613f);
    p = fmaf(p, w, 0.00943887047f);
    p = fmaf(p, w, 1.00167406f);
    p = fmaf(p, w, 2.83297682f);
  }
  return p * x;
}

__device__ inline float jax_normal_elem(uint32_t k0, uint32_t k1, uint32_t idx) {
  uint32_t o0, o1;
  threefry2x32(k0, k1, 0u, idx, &o0, &o1);
  uint32_t bits = o0 ^ o1;
  float f = __uint_as_float((bits >> 9) | 0x3F800000u) - 1.0f;
  float u = f * 2.0f + (-0.99999994f);
  u = fmaxf(-0.99999994f, u);
  return 1.41421356237309505f * erfinv_f32(u);
}

__device__ inline float jax_normal_fast(uint32_t k0, uint32_t k1, uint32_t idx) {
  uint32_t o0, o1;
  threefry2x32(k0, k1, 0u, idx, &o0, &o1);
  uint32_t bits = o0 ^ o1;
  float f = __uint_as_float((bits >> 9) | 0x3F800000u) - 1.0f;
  float u = f * 2.0f + (-0.99999994f);
  u = fmaxf(-0.99999994f, u);
  return 1.41421356237309505f * erfinv_fast(u);
}

__device__ inline uint32_t f32_to_bf16_rne(float f) {
  uint32_t u = __float_as_uint(f);
  u += 0x7fffu + ((u >> 16) & 1u);
  return u >> 16;
}

// ---------------- Front kernel: hist4 | norm(out0 + bf16 mirror) ------------
__global__ __launch_bounds__(256) void front_kernel(
    const int* __restrict__ dst, int* __restrict__ counts,
    int* __restrict__ deg_hist, int E4, int E,
    const float* __restrict__ xin, float* __restrict__ out0,
    uint16_t* __restrict__ mir, int N, int nbHist) {
  int w = blockIdx.x;
  if (w < nbHist) {
    if (w == 0) {
      for (int bb = threadIdx.x; bb < 1024; bb += 256) deg_hist[bb] = 0;
    }
    int t = w * 256 + threadIdx.x;
    if (t < E4) {
      int4 d4 = ((const int4*)dst)[t];
      atomicAdd(&counts[d4.x], 1);
      atomicAdd(&counts[d4.y], 1);
      atomicAdd(&counts[d4.z], 1);
      atomicAdd(&counts[d4.w], 1);
    }
    int rem = E4 * 4 + t;
    if (t < E - E4 * 4) atomicAdd(&counts[dst[rem]], 1);
    return;
  }
  int t = (w - nbHist) * 256 + threadIdx.x;
  int row = t >> 6;
  int lane = t & 63;
  if (row >= N) return;
  size_t base = (size_t)row * D + 2 * lane;
  float2 v = *(const float2*)(xin + base);
  float ss = v.x * v.x + v.y * v.y;
#pragma unroll
  for (int off = 32; off > 0; off >>= 1) ss += __shfl_xor(ss, off);
  float denom = fmaxf(sqrtf(ss), 1e-12f);
  float2 o = make_float2(v.x / denom, v.y / denom);
  *(float2*)(out0 + base) = o;
  if (mir) {
    uint32_t wq = f32_to_bf16_rne(o.x) | (f32_to_bf16_rne(o.y) << 16);
    *(uint32_t*)(mir + base) = wq;
  }
}

// ---------------- CSR build (scans) -----------------------------------------
__global__ __launch_bounds__(256) void scanA_kernel(
    int* __restrict__ counts, int* __restrict__ blocksums,
    int* __restrict__ deg, int* __restrict__ deg_hist, int N) {
  __shared__ int tmp[256];
  __shared__ int lhist[1024];
  for (int b = threadIdx.x; b < 1024; b += 256) lhist[b] = 0;
  int tid = threadIdx.x;
  int i = blockIdx.x * 256 + tid;
  int v = (i < N) ? counts[i] : 0;
  tmp[tid] = v;
  __syncthreads();
  if (i < N) {
    deg[i] = v;
    atomicAdd(&lhist[min(v, 1023)], 1);
  }
  for (int off = 1; off < 256; off <<= 1) {
    int t = (tid >= off) ? tmp[tid - off] : 0;
    __syncthreads();
    tmp[tid] += t;
    __syncthreads();
  }
  if (i < N) counts[i] = tmp[tid] - v;  // exclusive
  if (tid == 255) blocksums[blockIdx.x] = tmp[tid];
  __syncthreads();
  for (int b = threadIdx.x; b < 1024; b += 256) {
    int c = lhist[b];
    if (c) atomicAdd(&deg_hist[b], c);
  }
}

__global__ __launch_bounds__(256) void scanB_kernel(
    int* __restrict__ blocksums, int nb,
    const int* __restrict__ deg_hist, int* __restrict__ deg_cursor) {
  __shared__ int tmp[256];
  int tid = threadIdx.x;
  int v = (tid < nb) ? blocksums[tid] : 0;
  tmp[tid] = v;
  __syncthreads();
  for (int off = 1; off < 256; off <<= 1) {
    int t = (tid >= off) ? tmp[tid - off] : 0;
    __syncthreads();
    tmp[tid] += t;
    __syncthreads();
  }
  if (tid < nb) blocksums[tid] = tmp[tid] - v;
  __syncthreads();
  int loc[4], s = 0;
#pragma unroll
  for (int k = 0; k < 4; ++k) { loc[k] = deg_hist[tid * 4 + k]; s += loc[k]; }
  __syncthreads();
  tmp[tid] = s;
  __syncthreads();
  for (int off = 1; off < 256; off <<= 1) {
    int t = (tid >= off) ? tmp[tid - off] : 0;
    __syncthreads();
    tmp[tid] += t;
    __syncthreads();
  }
  int run = tmp[tid] - s;
#pragma unroll
  for (int k = 0; k < 4; ++k) { deg_cursor[tid * 4 + k] = run; run += loc[k]; }
}

__global__ __launch_bounds__(256) void scanC_kernel(
    int* __restrict__ offsets, int* __restrict__ cursor,
    const int* __restrict__ blocksums, const int* __restrict__ deg,
    int* __restrict__ deg_cursor, int* __restrict__ perm, int N, int E) {
  __shared__ int lhist[1024];
  __shared__ int lbase[1024];
  for (int b = threadIdx.x; b < 1024; b += 256) lhist[b] = 0;
  __syncthreads();
  int i = blockIdx.x * 256 + threadIdx.x;
  int d = 0, lpos = 0;
  if (i < N) {
    int o = offsets[i] + blocksums[blockIdx.x];
    offsets[i] = o;
    cursor[i] = o;
    d = min(deg[i], 1023);
    lpos = atomicAdd(&lhist[d], 1);
  }
  if (i == 0) offsets[N] = E;
  __syncthreads();
  for (int b = threadIdx.x; b < 1024; b += 256) {
    int c = lhist[b];
    lbase[b] = c ? atomicAdd(&deg_cursor[b], c) : 0;
  }
  __syncthreads();
  if (i < N) perm[lbase[d] + lpos] = i;
}

// ---------------- Edge scatter, XCD-sliced by dst range ---------------------
// Round 5 counters: WRITE_SIZE 52.5 MB for a 3.2 MB logical output (16x
// line amplification: random 4B stores, lines co-written by multiple XCDs)
// -> 65 us. Fix: block bid handles only dst in slice (bid&7); consecutive
// blockIdx round-robins across the 8 XCDs, so each sorted_src/cursor region
// is written by ONE XCD's L2 -> full-line writebacks. Cost: edge list read
// 8x (51 MB) but streaming and LLC-served (6.4 MB << 256 MB L3).
__global__ __launch_bounds__(256) void edgescatter_sliced_kernel(
    const int* __restrict__ src, const int* __restrict__ dst,
    int* __restrict__ cursor, int* __restrict__ sorted_src,
    int E4, int E, int N) {
  int slice = blockIdx.x & 7;
  int chunk = blockIdx.x >> 3;
  int lo = (int)(((long long)N * slice) >> 3);
  int hi = (int)(((long long)N * (slice + 1)) >> 3);
  int t = chunk * 256 + threadIdx.x;
  if (t < E4) {
    int4 d = ((const int4*)dst)[t];
    int4 s = ((const int4*)src)[t];
    if (d.x >= lo && d.x < hi) sorted_src[atomicAdd(&cursor[d.x], 1)] = s.x;
    if (d.y >= lo && d.y < hi) sorted_src[atomicAdd(&cursor[d.y], 1)] = s.y;
    if (d.z >= lo && d.z < hi) sorted_src[atomicAdd(&cursor[d.z], 1)] = s.z;
    if (d.w >= lo && d.w < hi) sorted_src[atomicAdd(&cursor[d.w], 1)] = s.w;
  }
  int rem = E4 * 4 + t;
  if (t < E - E4 * 4) {
    int dd = dst[rem];
    if (dd >= lo && dd < hi)
      sorted_src[atomicAdd(&cursor[dd], 1)] = src[rem];
  }
}

// ---------------- Fused hop (bf16 gather): 16 lanes/row, 4 rows/wave --------
// Inline fast RNG (free under gather latency, verified r0 vs r3).
// __launch_bounds__(256,8): 32 waves/CU (verified win in round 5).
union V8 { float4 v[2]; v2f d[4]; float f[8]; };
union U4B { uint4 v; uint32_t u[4]; };

__device__ inline void hop_edge_pk(const U4B& raw, const V8& b, V8& acc) {
  V8 af;
#pragma unroll
  for (int i = 0; i < 4; ++i) {
    af.f[2 * i] = __uint_as_float(raw.u[i] << 16);
    af.f[2 * i + 1] = __uint_as_float(raw.u[i] & 0xffff0000u);
  }
  v2f p2 = af.d[0] * b.d[0];
#pragma unroll
  for (int q = 1; q < 4; ++q) p2 = __builtin_elementwise_fma(af.d[q], b.d[q], p2);
  float part = p2.x + p2.y;
  part += __shfl_xor(part, 1);
  part += __shfl_xor(part, 2);
  part += __shfl_xor(part, 4);
  part += __shfl_xor(part, 8);
  float alpha = __builtin_amdgcn_rcpf(1.0f + __expf(-part));
  v2f av = { alpha, alpha };
#pragma unroll
  for (int q = 0; q < 4; ++q) acc.d[q] = __builtin_elementwise_fma(av, af.d[q], acc.d[q]);
}

__global__ __launch_bounds__(256, 8) void hop_kernel_bf16(
    const float* __restrict__ hprev, const uint16_t* __restrict__ mprev,
    float* __restrict__ hout, uint16_t* __restrict__ mout,
    const int* __restrict__ offsets, const int* __restrict__ sorted_src,
    const int* __restrict__ perm, int N, int E, uint32_t k0, uint32_t k1) {
  int g = (blockIdx.x * blockDim.x + threadIdx.x) >> 4;
  int sub = threadIdx.x & 15;
  if (g >= N) return;
  int r = perm[g];
  size_t rbase = (size_t)r * D + sub * 8;

  V8 b;
  {
    const float4* p = (const float4*)(hprev + rbase);
    b.v[0] = p[0]; b.v[1] = p[1];
  }
  V8 acc;
#pragma unroll
  for (int i = 0; i < 8; ++i) acc.f[i] = 0.f;

  int j0 = offsets[r];
  int cnt = offsets[r + 1] - j0;
  int Em1 = E - 1;
  const char* mb = (const char*)mprev + (uint32_t)(sub * 16);

  U4B buf[4];
  int sNext[4];
#pragma unroll
  for (int q = 0; q < 4; ++q) {
    uint32_t s = (uint32_t)sorted_src[min(j0 + q, Em1)];
    buf[q].v = *(const uint4*)(mb + (s << 8));
  }
#pragma unroll
  for (int q = 0; q < 4; ++q) sNext[q] = sorted_src[min(j0 + 4 + q, Em1)];

  int cnt4 = cnt & ~3;
  for (int i = 0; i < cnt4; i += 4) {
#pragma unroll
    for (int q = 0; q < 4; ++q) {
      hop_edge_pk(buf[q], b, acc);                                 // row i+q
      buf[q].v = *(const uint4*)(mb + ((uint32_t)sNext[q] << 8));  // row i+4+q
      sNext[q] = sorted_src[min(j0 + i + 8 + q, Em1)];             // row i+8+q
    }
  }
  int rem = cnt - cnt4;
#pragma unroll
  for (int q = 0; q < 3; ++q)
    if (q < rem) hop_edge_pk(buf[q], b, acc);

  // inline noise (bit-exact jax.random.normal, fast-log variant) + normalize
  uint32_t idx = (uint32_t)rbase;
  float ss = 0.f;
#pragma unroll
  for (int i2 = 0; i2 < 8; ++i2) {
    acc.f[i2] += 0.1f * jax_normal_fast(k0, k1, idx + (uint32_t)i2);
    ss = fmaf(acc.f[i2], acc.f[i2], ss);
  }
  ss += __shfl_xor(ss, 1);
  ss += __shfl_xor(ss, 2);
  ss += __shfl_xor(ss, 4);
  ss += __shfl_xor(ss, 8);
  float denom = fmaxf(sqrtf(ss), 1e-12f);
  float inv = __builtin_amdgcn_rcpf(denom);
  inv = inv * fmaf(-denom, inv, 2.0f);  // one NR step -> ~0.5 ulp
#pragma unroll
  for (int i2 = 0; i2 < 8; ++i2) acc.f[i2] *= inv;
  {
    float4* p = (float4*)(hout + rbase);
    p[0] = acc.v[0]; p[1] = acc.v[1];
  }
  if (mout) {
    U4B wq;
#pragma unroll
    for (int i2 = 0; i2 < 4; ++i2)
      wq.u[i2] = f32_to_bf16_rne(acc.f[2 * i2]) |
                 (f32_to_bf16_rne(acc.f[2 * i2 + 1]) << 16);
    *(uint4*)(mout + rbase) = wq.v;
  }
}

// ---------------- Fallback hop (f32 gather, no-workspace path) --------------
union V16 { float4 v[4]; float f[16]; };

__global__ __launch_bounds__(256) void hop_kernel_f32(
    const float* __restrict__ hprev, float* __restrict__ hout,
    const int* __restrict__ offsets, const int* __restrict__ sorted_src,
    const int* __restrict__ perm, int N, uint32_t k0, uint32_t k1) {
  int g = (blockIdx.x * blockDim.x + threadIdx.x) >> 3;
  int sub = threadIdx.x & 7;
  if (g >= N) return;
  int r = perm[g];
  size_t rbase = (size_t)r * D + sub * 16;

  V16 b;
  {
    const float4* p = (const float4*)(hprev + rbase);
    b.v[0] = p[0]; b.v[1] = p[1]; b.v[2] = p[2]; b.v[3] = p[3];
  }
  V16 acc;
#pragma unroll
  for (int i = 0; i < 16; ++i) acc.f[i] = 0.f;

  int j = offsets[r], jhi = offsets[r + 1];
  V16 a;
  if (j < jhi) {
    const float4* p = (const float4*)(hprev + (size_t)sorted_src[j] * D + sub * 16);
    a.v[0] = p[0]; a.v[1] = p[1]; a.v[2] = p[2]; a.v[3] = p[3];
  }
  while (j < jhi) {
    int jn = j + 1;
    V16 an;
    if (jn < jhi) {
      const float4* p = (const float4*)(hprev + (size_t)sorted_src[jn] * D + sub * 16);
      an.v[0] = p[0]; an.v[1] = p[1]; an.v[2] = p[2]; an.v[3] = p[3];
    }
    float part = a.f[0] * b.f[0];
#pragma unroll
    for (int i = 1; i < 16; ++i) part = fmaf(a.f[i], b.f[i], part);
    part += __shfl_xor(part, 1);
    part += __shfl_xor(part, 2);
    part += __shfl_xor(part, 4);
    float alpha = 1.0f / (1.0f + expf(-part));
#pragma unroll
    for (int i = 0; i < 16; ++i) acc.f[i] = fmaf(alpha, a.f[i], acc.f[i]);
    a = an;
    j = jn;
  }

  uint32_t idx = (uint32_t)rbase;
  float ss = 0.f;
#pragma unroll
  for (int i = 0; i < 16; ++i) {
    acc.f[i] += 0.1f * jax_normal_elem(k0, k1, idx + (uint32_t)i);
    ss = fmaf(acc.f[i], acc.f[i], ss);
  }
  ss += __shfl_xor(ss, 1);
  ss += __shfl_xor(ss, 2);
  ss += __shfl_xor(ss, 4);
  float denom = fmaxf(sqrtf(ss), 1e-12f);
#pragma unroll
  for (int i = 0; i < 16; ++i) acc.f[i] = acc.f[i] / denom;
  {
    float4* p = (float4*)(hout + rbase);
    p[0] = acc.v[0]; p[1] = acc.v[1]; p[2] = acc.v[2]; p[3] = acc.v[3];
  }
}

// ============================ host launcher =================================
extern "C" void kernel_launch(void* const* d_in, const int* in_sizes, int n_in,
                              void* d_out, int out_size, void* d_ws, size_t ws_size,
                              hipStream_t stream) {
  const float* x = (const float*)d_in[0];
  const int* ei = (const int*)d_in[1];
  int N = in_sizes[0] / D;   // 50000
  int E = in_sizes[1] / 2;   // 800000
  const int* src = ei;
  const int* dst = ei + E;
  float* out = (float*)d_out;
  size_t ND = (size_t)N * D;

  int nblocksN = (N + 255) / 256;

  // ws layout (ints): offsets[N+1] | cursor[N] | perm[N] | deg[N]
  //                 | deg_hist[1024] | deg_cursor[1024] | blocksums[256]
  //                 | sorted_src[E]
  //   then (256B aligned): bf16 mirrors mir0[N*D], mir1[N*D]
  int* offsets = (int*)d_ws;
  int* cursor = offsets + (N + 1);
  int* perm = cursor + N;
  int* deg = perm + N;
  int* deg_hist = deg + N;
  int* deg_cursor = deg_hist + 1024;
  int* blocksums = deg_cursor + 1024;
  int* sorted_src = blocksums + 256;
  size_t intWords = (size_t)(N + 1) + N + N + N + 1024 + 1024 + 256 + E;
  size_t mirOff = (intWords * 4 + 255) & ~(size_t)255;
  size_t needMir = mirOff + 2 * ND * sizeof(uint16_t);
  bool use_bf16 = ws_size >= needMir;
  uint16_t* mir0 = (uint16_t*)((char*)d_ws + mirOff);
  uint16_t* mir1 = mir0 + ND;

  // noise_keys = jax.random.split(jax.random.key(1), 3)
  uint32_t nk0[3], nk1[3];
  for (int k = 0; k < 3; ++k)
    threefry2x32(0u, 1u, 0u, (uint32_t)k, &nk0[k], &nk1[k]);

  int E4 = E / 4;
  int e4Blocks = (max(E4, E - E4 * 4) + 255) / 256;
  int rowWaveBlocks = (int)(((size_t)N * 64 + 255) / 256);  // 1 wave/row (norm)
  int hopBlocks16 = (int)(((size_t)N * 16 + 255) / 256);    // 16 lanes/row
  int hopBlocks8 = (int)(((size_t)N * 8 + 255) / 256);      // 8 lanes/row

  // ---- front: hist + norm(+mirror) fused ----
  hipMemsetAsync(offsets, 0, (size_t)(N + 1) * sizeof(int), stream);
  hipLaunchKernelGGL(front_kernel, dim3(e4Blocks + rowWaveBlocks), dim3(256), 0,
                     stream, dst, offsets, deg_hist, E4, E,
                     x, out, use_bf16 ? mir0 : (uint16_t*)nullptr, N, e4Blocks);
  hipLaunchKernelGGL(scanA_kernel, dim3(nblocksN), dim3(256), 0, stream,
                     offsets, blocksums, deg, deg_hist, N);
  hipLaunchKernelGGL(scanB_kernel, dim3(1), dim3(256), 0, stream,
                     blocksums, nblocksN, deg_hist, deg_cursor);
  hipLaunchKernelGGL(scanC_kernel, dim3(nblocksN), dim3(256), 0, stream,
                     offsets, cursor, blocksums, deg, deg_cursor, perm, N, E);
  hipLaunchKernelGGL(edgescatter_sliced_kernel, dim3(8 * e4Blocks), dim3(256),
                     0, stream, src, dst, cursor, sorted_src, E4, E, N);

  if (use_bf16) {
    uint16_t* mirs[4] = {mir0, mir1, mir0, nullptr};  // last hop: no mirror out
    for (int k = 0; k < 3; ++k) {
      const float* hk = out + (size_t)k * ND;
      float* hk1 = out + (size_t)(k + 1) * ND;
      hipLaunchKernelGGL(hop_kernel_bf16, dim3(hopBlocks16), dim3(256), 0,
                         stream, hk, mirs[k], hk1, mirs[k + 1], offsets,
                         sorted_src, perm, N, E, nk0[k], nk1[k]);
    }
  } else {
    for (int k = 0; k < 3; ++k) {
      const float* hk = out + (size_t)k * ND;
      float* hk1 = out + (size_t)(k + 1) * ND;
      hipLaunchKernelGGL(hop_kernel_f32, dim3(hopBlocks8), dim3(256), 0, stream,
                         hk, hk1, offsets, sorted_src, perm, N, nk0[k], nk1[k]);
    }
  }
}